// Round 10
// baseline (207.756 us; speedup 1.0000x reference)
//
#include <hip/hip_runtime.h>
#include <hip/hip_bf16.h>

typedef __attribute__((ext_vector_type(8))) short short8;
typedef __attribute__((ext_vector_type(4))) float v4f;

// async global->LDS, 16B per lane. LDS dest must be wave-uniform base + lane*16.
#define ASYNC_COPY16(ldsptr, gptr)                                                        \
  __builtin_amdgcn_global_load_lds((const __attribute__((address_space(1))) void*)(gptr), \
                                   (__attribute__((address_space(3))) void*)(ldsptr),     \
                                   16, 0, 0)

__device__ __forceinline__ unsigned short f2bf(float f) {
  unsigned int u = __float_as_uint(f);
  u += 0x7fffu + ((u >> 16) & 1u);  // RNE
  return (unsigned short)(u >> 16);
}

// ---------------- fused fp32 -> bf16 convert for all three inputs ----------------
__global__ void convert_all(const float* __restrict__ h, const float* __restrict__ wq,
                            const float* __restrict__ wo, unsigned short* __restrict__ ho,
                            unsigned short* __restrict__ wqo, unsigned short* __restrict__ woo) {
  int i = (blockIdx.x * blockDim.x + threadIdx.x) * 4;
  const float* src;
  unsigned short* dst;
  int j;
  if (i < 4194304) { src = h; dst = ho; j = i; }
  else if (i < 7340032) { src = wq; dst = wqo; j = i - 4194304; }
  else { src = wo; dst = woo; j = i - 7340032; }
  float4 v = *(const float4*)(src + j);
  ushort4 o;
  o.x = f2bf(v.x); o.y = f2bf(v.y); o.z = f2bf(v.z); o.w = f2bf(v.w);
  *(ushort4*)(dst + j) = o;
}

// ---------------- bf16 GEMM, C[m][n] = sum_k A[m][k]*B[n][k], fp32 out -------------
template <int BN>
__global__ __launch_bounds__(256) void gemm_bt(const unsigned short* __restrict__ A,
                                               const unsigned short* __restrict__ Bm,
                                               float* __restrict__ C, int M, int N, int K) {
  constexpr int WN = BN / 2;
  constexpr int JN = WN / 16;
  __shared__ __attribute__((aligned(16))) unsigned short As[128 * 32];
  __shared__ __attribute__((aligned(16))) unsigned short Bs[BN * 32];
  int t = threadIdx.x;
  int w = t >> 6, lane = t & 63, kb = lane >> 4, lr = lane & 15;
  int m0 = blockIdx.y * 128, n0 = blockIdx.x * BN;
  int wm = (w >> 1) * 64, wn = (w & 1) * WN;
  v4f acc[4][JN];
#pragma unroll
  for (int i = 0; i < 4; i++)
#pragma unroll
    for (int j = 0; j < JN; j++) acc[i][j] = (v4f){0.f, 0.f, 0.f, 0.f};
  int ra = m0 + (t >> 2);
  int rb = n0 + (t >> 2);
  int ca = (t & 3) * 8;
  for (int k0 = 0; k0 < K; k0 += 32) {
    ASYNC_COPY16(&As[t * 8],        A + (size_t)ra * K + k0 + ca);
    ASYNC_COPY16(&As[2048 + t * 8], A + (size_t)(ra + 64) * K + k0 + ca);
#pragma unroll
    for (int c = 0; c < BN / 64; c++)
      ASYNC_COPY16(&Bs[c * 2048 + t * 8], Bm + (size_t)(rb + c * 64) * K + k0 + ca);
    __syncthreads();
    short8 av[4], bv[JN];
#pragma unroll
    for (int i = 0; i < 4; i++) av[i] = *(const short8*)&As[(wm + i * 16 + lr) * 32 + kb * 8];
#pragma unroll
    for (int j = 0; j < JN; j++) bv[j] = *(const short8*)&Bs[(wn + j * 16 + lr) * 32 + kb * 8];
#pragma unroll
    for (int i = 0; i < 4; i++)
#pragma unroll
      for (int j = 0; j < JN; j++)
        acc[i][j] = __builtin_amdgcn_mfma_f32_16x16x32_bf16(av[i], bv[j], acc[i][j], 0, 0, 0);
    __syncthreads();
  }
#pragma unroll
  for (int i = 0; i < 4; i++) {
    int row = m0 + wm + i * 16 + kb * 4;
#pragma unroll
    for (int j = 0; j < JN; j++) {
      int col = n0 + wn + j * 16 + lr;
#pragma unroll
      for (int r = 0; r < 4; r++) C[(size_t)(row + r) * N + col] = acc[i][j][r];
    }
  }
}

// ---------- QKV GEMM with FUSED rope + head-split + V-transpose epilogue -----------
// C = hidden @ w_qkv.T (M=4096, N=3072, K=1024). Since 384 = 3*128, each
// 128-wide n-tile is purely q (type 0), v (1), or k (2): type = (n0/128)%3,
// mp = n0/384. Epilogue applies RoPE to q/k (pair exchange via shfl_xor(1),
// angle from seq pos = m&2047) and writes Q (pre-scaled by log2e/8), K, and
// key-permuted transposed Vt directly -- the standalone rope_vt kernel and the
// 48 MB qkv round-trip are gone.
__global__ __launch_bounds__(256) void gemm_qkv(const unsigned short* __restrict__ A,
                                                const unsigned short* __restrict__ Bm,
                                                unsigned short* __restrict__ Q,
                                                unsigned short* __restrict__ Ko,
                                                unsigned short* __restrict__ Vt) {
  constexpr int Kd = 1024;
  __shared__ __attribute__((aligned(16))) unsigned short As[128 * 32];
  __shared__ __attribute__((aligned(16))) unsigned short Bs[128 * 32];
  int t = threadIdx.x;
  int w = t >> 6, lane = t & 63, kb = lane >> 4, lr = lane & 15;
  int m0 = blockIdx.y * 128, n0 = blockIdx.x * 128;
  int wm = (w >> 1) * 64, wn = (w & 1) * 64;
  v4f acc[4][4];
#pragma unroll
  for (int i = 0; i < 4; i++)
#pragma unroll
    for (int j = 0; j < 4; j++) acc[i][j] = (v4f){0.f, 0.f, 0.f, 0.f};
  int ra = m0 + (t >> 2);
  int rb = n0 + (t >> 2);
  int ca = (t & 3) * 8;
  for (int k0 = 0; k0 < Kd; k0 += 32) {
    ASYNC_COPY16(&As[t * 8],        A + (size_t)ra * Kd + k0 + ca);
    ASYNC_COPY16(&As[2048 + t * 8], A + (size_t)(ra + 64) * Kd + k0 + ca);
    ASYNC_COPY16(&Bs[t * 8],        Bm + (size_t)rb * Kd + k0 + ca);
    ASYNC_COPY16(&Bs[2048 + t * 8], Bm + (size_t)(rb + 64) * Kd + k0 + ca);
    __syncthreads();
    short8 av[4], bv[4];
#pragma unroll
    for (int i = 0; i < 4; i++) av[i] = *(const short8*)&As[(wm + i * 16 + lr) * 32 + kb * 8];
#pragma unroll
    for (int j = 0; j < 4; j++) bv[j] = *(const short8*)&Bs[(wn + j * 16 + lr) * 32 + kb * 8];
#pragma unroll
    for (int i = 0; i < 4; i++)
#pragma unroll
      for (int j = 0; j < 4; j++)
        acc[i][j] = __builtin_amdgcn_mfma_f32_16x16x32_bf16(av[i], bv[j], acc[i][j], 0, 0, 0);
    __syncthreads();
  }
  // ---- fused epilogue ----
  int X = n0 >> 7;
  int mp = X / 3;
  int type = X - mp * 3;     // 0=q, 1=v, 2=k  (block-uniform)
  int ii = wn >> 6;
  int h = mp * 2 + ii;
  const float qs = 0.125f * 1.4426950408889634f;  // 1/sqrt(64) * log2(e)
  if (type == 1) {
    // V: Vt[bh][dim][perm(s)], perm = (s&~31) | ((s&15)<<1) | ((s>>4)&1)
#pragma unroll
    for (int i = 0; i < 4; i++) {
      int row = m0 + wm + i * 16 + kb * 4;
#pragma unroll
      for (int j = 0; j < 4; j++) {
        int dim = j * 16 + lr;
#pragma unroll
        for (int r = 0; r < 4; r++) {
          int m = row + r;
          int b = m >> 11, sl = m & 2047;
          int bh = b * 16 + h;
          int p = (sl & ~31) | ((sl & 15) << 1) | ((sl >> 4) & 1);
          Vt[(size_t)bh * 131072 + (size_t)dim * 2048 + p] = f2bf(acc[i][j][r]);
        }
      }
    }
  } else {
    unsigned short* dst = (type == 0) ? Q : Ko;
    float scale = (type == 0) ? qs : 1.0f;
#pragma unroll
    for (int i = 0; i < 4; i++) {
      int row = m0 + wm + i * 16 + kb * 4;
#pragma unroll
      for (int j = 0; j < 4; j++) {
        int dim = j * 16 + lr;
        float vals[4];
#pragma unroll
        for (int r = 0; r < 4; r++) vals[r] = acc[i][j][r];
        if (j < 2) {  // dims 0..31: rotary
          int jp = dim >> 1;
          float invf = expf(-(float)jp * 0.57564627324851142f);
#pragma unroll
          for (int r = 0; r < 4; r++) {
            int sl = (row + r) & 2047;  // sequence position
            float ang = (float)sl * invf;
            float sn, cs;
            sincosf(ang, &sn, &cs);
            float partner = __shfl_xor(vals[r], 1);
            float self = vals[r] * cs;
            vals[r] = (lr & 1) ? fmaf(partner, sn, self) : fmaf(-partner, sn, self);
          }
        }
#pragma unroll
        for (int r = 0; r < 4; r++) {
          int m = row + r;
          int b = m >> 11, sl = m & 2047;
          int bh = b * 16 + h;
          dst[(((size_t)(bh * 2048 + sl)) << 6) + dim] = f2bf(vals[r] * scale);
        }
      }
    }
  }
}

// ---------------- fused causal flash attention, v10 = v9 + XCD-aware bh map -------
// v7/v9 core (4 waves x 16 q-rows, 32-key tiles, dbuf async staging, 21504 B
// LDS, conflict-free layouts, per-CU-uniform qtile quarters {z,31-z,z+8,23-z}
// summing 132). NEW: bh = (gid&7)*4 + ((gid>>3)&3) -> under block->XCD
// round-robin (i%8), each XCD sees only 4 bh => Q/K/V working set ~3 MB fits
// the 4 MB per-XCD L2 (v9 spread all 32 bh across every XCD -> 2.6x refetch).
__global__ __launch_bounds__(256, 6) void attn_fused(const unsigned short* __restrict__ Qg,
                                                     const unsigned short* __restrict__ Kg,
                                                     const unsigned short* __restrict__ Vtg,
                                                     unsigned short* __restrict__ AO) {
  __shared__ __attribute__((aligned(16))) unsigned short Ks[2 * 2048];  // 8 KB
  __shared__ __attribute__((aligned(16))) unsigned short Vs[2 * 2048];  // 8 KB
  __shared__ __attribute__((aligned(16))) unsigned short Ps[4 * 16 * 40];  // 5 KB
  int t = threadIdx.x;
  int w = t >> 6, lane = t & 63, kb = lane >> 4, lr = lane & 15;
  int gid = blockIdx.x;
  int g3 = gid & 7;
  int b2 = (gid >> 3) & 3;
  int z = (gid >> 5) & 7;
  int quarter = gid >> 8;
  int bh = g3 * 4 + b2;
  int qtile = (quarter == 0) ? z : (quarter == 1) ? (31 - z) : (quarter == 2) ? (z + 8) : (23 - z);
  int m0 = qtile * 64;
  const unsigned short* Qb = Qg + (size_t)bh * 2048 * 64;
  const unsigned short* Kb = Kg + (size_t)bh * 2048 * 64;
  const unsigned short* Vb = Vtg + (size_t)bh * 64 * 2048;

  // Q A-fragments straight from global: rows m0 + w*16 + lr
  short8 aq0 = *(const short8*)(Qb + (size_t)(m0 + w * 16 + lr) * 64 + kb * 8);
  short8 aq1 = *(const short8*)(Qb + (size_t)(m0 + w * 16 + lr) * 64 + 32 + kb * 8);

  v4f acc[4];
  float lp[4];
#pragma unroll
  for (int n = 0; n < 4; n++) acc[n] = (v4f){0.f, 0.f, 0.f, 0.f};
#pragma unroll
  for (int r = 0; r < 4; r++) lp[r] = 0.f;

  int nkt = 2 * qtile + 2;  // 32-key tiles
  int mrow = w * 16 + kb * 4;

  int kc = t >> 5, krow_s = t & 31;
  int vc = t >> 6, vd = t & 63;
  auto stage = [&](int kt, int buf) {
    int base = buf * 2048;
    ASYNC_COPY16(&Ks[base + t * 8], Kb + (size_t)(kt * 32 + krow_s) * 64 + kc * 8);
    ASYNC_COPY16(&Vs[base + t * 8], Vb + (size_t)vd * 2048 + kt * 32 + vc * 8);
  };

  stage(0, 0);
  __syncthreads();

  unsigned short* Pw = &Ps[w * 640];
  for (int kt = 0; kt < nkt; kt++) {
    int cur = (kt & 1) * 2048;
    if (kt + 1 < nkt) stage(kt + 1, (kt + 1) & 1);
    v4f sc[2];
#pragma unroll
    for (int n2 = 0; n2 < 2; n2++) {
      int krow = n2 * 16 + lr;
      short8 bk0 = *(const short8*)&Ks[cur + (kb * 32 + krow) * 8];
      short8 bk1 = *(const short8*)&Ks[cur + ((kb + 4) * 32 + krow) * 8];
      v4f zz = (v4f){0.f, 0.f, 0.f, 0.f};
      zz = __builtin_amdgcn_mfma_f32_16x16x32_bf16(aq0, bk0, zz, 0, 0, 0);
      zz = __builtin_amdgcn_mfma_f32_16x16x32_bf16(aq1, bk1, zz, 0, 0, 0);
      sc[n2] = zz;
    }
    if (kt >= 2 * qtile) {
#pragma unroll
      for (int n2 = 0; n2 < 2; n2++)
#pragma unroll
        for (int r = 0; r < 4; r++) {
          int key = kt * 32 + n2 * 16 + lr;
          if (key > m0 + mrow + r) sc[n2][r] = -1e30f;
        }
    }
#pragma unroll
    for (int r = 0; r < 4; r++) {
      float p0 = exp2f(sc[0][r]);
      float p1 = exp2f(sc[1][r]);
      lp[r] += p0 + p1;
      __hip_bfloat162 pb = __float22bfloat162_rn(float2{p0, p1});
      *(__hip_bfloat162*)&Pw[(mrow & 15) * 40 + r * 40 + lr * 2] = pb;
    }
    short8 ap = *(const short8*)&Pw[lr * 40 + kb * 8];
#pragma unroll
    for (int dt = 0; dt < 4; dt++) {
      int d = dt * 16 + lr;
      short8 bv = *(const short8*)&Vs[cur + (kb * 64 + d) * 8];
      acc[dt] = __builtin_amdgcn_mfma_f32_16x16x32_bf16(ap, bv, acc[dt], 0, 0, 0);
    }
    __syncthreads();
  }
  int b = bh >> 4, h = bh & 15;
#pragma unroll
  for (int r = 0; r < 4; r++) {
    float s = lp[r];
#pragma unroll
    for (int off = 1; off < 16; off <<= 1) s += __shfl_xor(s, off);
    float inv = 1.0f / s;
    int qrow = m0 + mrow + r;
#pragma unroll
    for (int dt = 0; dt < 4; dt++)
      AO[(size_t)(b * 2048 + qrow) * 1024 + h * 64 + dt * 16 + lr] = f2bf(acc[dt][r] * inv);
  }
}

extern "C" void kernel_launch(void* const* d_in, const int* in_sizes, int n_in,
                              void* d_out, int out_size, void* d_ws, size_t ws_size,
                              hipStream_t stream) {
  const float* hidden = (const float*)d_in[0];
  const float* w_qkv = (const float*)d_in[1];
  const float* w_out = (const float*)d_in[2];
  float* out = (float*)d_out;
  char* ws = (char*)d_ws;
  unsigned short* hid_bf = (unsigned short*)(ws);                  //  8 MB
  unsigned short* wqkv_bf = (unsigned short*)(ws + (8ull << 20));  //  6 MB
  unsigned short* wout_bf = (unsigned short*)(ws + (14ull << 20)); //  2 MB
  unsigned short* Qb = (unsigned short*)(ws + (16ull << 20));      //  8 MB
  unsigned short* Kb = (unsigned short*)(ws + (24ull << 20));      //  8 MB
  unsigned short* Vt = (unsigned short*)(ws + (32ull << 20));      //  8 MB
  unsigned short* AO = (unsigned short*)(ws + (40ull << 20));      //  8 MB

  convert_all<<<8192, 256, 0, stream>>>(hidden, w_qkv, w_out, hid_bf, wqkv_bf, wout_bf);
  // qkv GEMM with fused rope/head-split/V-transpose epilogue
  gemm_qkv<<<dim3(24, 32), 256, 0, stream>>>(hid_bf, wqkv_bf, Qb, Kb, Vt);
  attn_fused<<<1024, 256, 0, stream>>>(Qb, Kb, Vt, AO);
  // out = attn_out @ w_out.T  (M=4096, N=1024, K=1024), fp32 out, 128x64 tiles
  gemm_bt<64><<<dim3(16, 32), 256, 0, stream>>>(AO, wout_bf, out, 4096, 1024, 1024);
}

// Round 11
// 205.936 us; speedup vs baseline: 1.0088x; 1.0088x over previous
//
#include <hip/hip_runtime.h>
#include <hip/hip_bf16.h>

typedef __attribute__((ext_vector_type(8))) short short8;
typedef __attribute__((ext_vector_type(4))) float v4f;

// async global->LDS, 16B per lane. LDS dest must be wave-uniform base + lane*16.
#define ASYNC_COPY16(ldsptr, gptr)                                                        \
  __builtin_amdgcn_global_load_lds((const __attribute__((address_space(1))) void*)(gptr), \
                                   (__attribute__((address_space(3))) void*)(ldsptr),     \
                                   16, 0, 0)

__device__ __forceinline__ unsigned short f2bf(float f) {
  unsigned int u = __float_as_uint(f);
  u += 0x7fffu + ((u >> 16) & 1u);  // RNE
  return (unsigned short)(u >> 16);
}

// ---------------- fused fp32 -> bf16 convert for all three inputs ----------------
__global__ void convert_all(const float* __restrict__ h, const float* __restrict__ wq,
                            const float* __restrict__ wo, unsigned short* __restrict__ ho,
                            unsigned short* __restrict__ wqo, unsigned short* __restrict__ woo) {
  int i = (blockIdx.x * blockDim.x + threadIdx.x) * 4;
  const float* src;
  unsigned short* dst;
  int j;
  if (i < 4194304) { src = h; dst = ho; j = i; }
  else if (i < 7340032) { src = wq; dst = wqo; j = i - 4194304; }
  else { src = wo; dst = woo; j = i - 7340032; }
  float4 v = *(const float4*)(src + j);
  ushort4 o;
  o.x = f2bf(v.x); o.y = f2bf(v.y); o.z = f2bf(v.z); o.w = f2bf(v.w);
  *(ushort4*)(dst + j) = o;
}

// GEMM LDS bank swizzle: global chunk c of local row r lives at LDS chunk
// c ^ ((r>>1)&3). Fragment reads then hit bank (lr&1)*16 + (kb^((lr>>1)&3))*4:
// 16 lanes -> 8 bank-groups x2 = free 2-way (was 8-way: 3.1e6 conflicts, x2.9).
#define STAGE_SWZ(tt) ((((tt) & 3) ^ (((tt) >> 3) & 3)) * 8)
#define READ_SWZ(kb, lr) (((kb) ^ (((lr) >> 1) & 3)) * 8)

// ---------------- bf16 GEMM, C[m][n] = sum_k A[m][k]*B[n][k], fp32 out -------------
template <int BN>
__global__ __launch_bounds__(256) void gemm_bt(const unsigned short* __restrict__ A,
                                               const unsigned short* __restrict__ Bm,
                                               float* __restrict__ C, int M, int N, int K) {
  constexpr int WN = BN / 2;
  constexpr int JN = WN / 16;
  __shared__ __attribute__((aligned(16))) unsigned short As[128 * 32];
  __shared__ __attribute__((aligned(16))) unsigned short Bs[BN * 32];
  int t = threadIdx.x;
  int w = t >> 6, lane = t & 63, kb = lane >> 4, lr = lane & 15;
  int m0 = blockIdx.y * 128, n0 = blockIdx.x * BN;
  int wm = (w >> 1) * 64, wn = (w & 1) * WN;
  v4f acc[4][JN];
#pragma unroll
  for (int i = 0; i < 4; i++)
#pragma unroll
    for (int j = 0; j < JN; j++) acc[i][j] = (v4f){0.f, 0.f, 0.f, 0.f};
  int ra = m0 + (t >> 2);
  int rb = n0 + (t >> 2);
  int ca = STAGE_SWZ(t);
  int rs = READ_SWZ(kb, lr);
  for (int k0 = 0; k0 < K; k0 += 32) {
    ASYNC_COPY16(&As[t * 8],        A + (size_t)ra * K + k0 + ca);
    ASYNC_COPY16(&As[2048 + t * 8], A + (size_t)(ra + 64) * K + k0 + ca);
#pragma unroll
    for (int c = 0; c < BN / 64; c++)
      ASYNC_COPY16(&Bs[c * 2048 + t * 8], Bm + (size_t)(rb + c * 64) * K + k0 + ca);
    __syncthreads();
    short8 av[4], bv[JN];
#pragma unroll
    for (int i = 0; i < 4; i++) av[i] = *(const short8*)&As[(wm + i * 16 + lr) * 32 + rs];
#pragma unroll
    for (int j = 0; j < JN; j++) bv[j] = *(const short8*)&Bs[(wn + j * 16 + lr) * 32 + rs];
#pragma unroll
    for (int i = 0; i < 4; i++)
#pragma unroll
      for (int j = 0; j < JN; j++)
        acc[i][j] = __builtin_amdgcn_mfma_f32_16x16x32_bf16(av[i], bv[j], acc[i][j], 0, 0, 0);
    __syncthreads();
  }
#pragma unroll
  for (int i = 0; i < 4; i++) {
    int row = m0 + wm + i * 16 + kb * 4;
#pragma unroll
    for (int j = 0; j < JN; j++) {
      int col = n0 + wn + j * 16 + lr;
#pragma unroll
      for (int r = 0; r < 4; r++) C[(size_t)(row + r) * N + col] = acc[i][j][r];
    }
  }
}

// ---------- QKV GEMM with FUSED rope + head-split + V-transpose epilogue -----------
// C = hidden @ w_qkv.T (M=4096, N=3072, K=1024). Since 384 = 3*128, each
// 128-wide n-tile is purely q (type 0), v (1), or k (2): type = (n0/128)%3,
// mp = n0/384. Epilogue applies RoPE to q/k (pair exchange via shfl_xor(1),
// angle from seq pos = m&2047) and writes Q (pre-scaled by log2e/8), K, and
// key-permuted transposed Vt directly.
__global__ __launch_bounds__(256) void gemm_qkv(const unsigned short* __restrict__ A,
                                                const unsigned short* __restrict__ Bm,
                                                unsigned short* __restrict__ Q,
                                                unsigned short* __restrict__ Ko,
                                                unsigned short* __restrict__ Vt) {
  constexpr int Kd = 1024;
  __shared__ __attribute__((aligned(16))) unsigned short As[128 * 32];
  __shared__ __attribute__((aligned(16))) unsigned short Bs[128 * 32];
  int t = threadIdx.x;
  int w = t >> 6, lane = t & 63, kb = lane >> 4, lr = lane & 15;
  int m0 = blockIdx.y * 128, n0 = blockIdx.x * 128;
  int wm = (w >> 1) * 64, wn = (w & 1) * 64;
  v4f acc[4][4];
#pragma unroll
  for (int i = 0; i < 4; i++)
#pragma unroll
    for (int j = 0; j < 4; j++) acc[i][j] = (v4f){0.f, 0.f, 0.f, 0.f};
  int ra = m0 + (t >> 2);
  int rb = n0 + (t >> 2);
  int ca = STAGE_SWZ(t);
  int rs = READ_SWZ(kb, lr);
  for (int k0 = 0; k0 < Kd; k0 += 32) {
    ASYNC_COPY16(&As[t * 8],        A + (size_t)ra * Kd + k0 + ca);
    ASYNC_COPY16(&As[2048 + t * 8], A + (size_t)(ra + 64) * Kd + k0 + ca);
    ASYNC_COPY16(&Bs[t * 8],        Bm + (size_t)rb * Kd + k0 + ca);
    ASYNC_COPY16(&Bs[2048 + t * 8], Bm + (size_t)(rb + 64) * Kd + k0 + ca);
    __syncthreads();
    short8 av[4], bv[4];
#pragma unroll
    for (int i = 0; i < 4; i++) av[i] = *(const short8*)&As[(wm + i * 16 + lr) * 32 + rs];
#pragma unroll
    for (int j = 0; j < 4; j++) bv[j] = *(const short8*)&Bs[(wn + j * 16 + lr) * 32 + rs];
#pragma unroll
    for (int i = 0; i < 4; i++)
#pragma unroll
      for (int j = 0; j < 4; j++)
        acc[i][j] = __builtin_amdgcn_mfma_f32_16x16x32_bf16(av[i], bv[j], acc[i][j], 0, 0, 0);
    __syncthreads();
  }
  // ---- fused epilogue ----
  int X = n0 >> 7;
  int mp = X / 3;
  int type = X - mp * 3;     // 0=q, 1=v, 2=k  (block-uniform)
  int ii = wn >> 6;
  int h = mp * 2 + ii;
  const float qs = 0.125f * 1.4426950408889634f;  // 1/sqrt(64) * log2(e)
  if (type == 1) {
    // V: Vt[bh][dim][perm(s)], perm = (s&~31) | ((s&15)<<1) | ((s>>4)&1)
#pragma unroll
    for (int i = 0; i < 4; i++) {
      int row = m0 + wm + i * 16 + kb * 4;
#pragma unroll
      for (int j = 0; j < 4; j++) {
        int dim = j * 16 + lr;
#pragma unroll
        for (int r = 0; r < 4; r++) {
          int m = row + r;
          int b = m >> 11, sl = m & 2047;
          int bh = b * 16 + h;
          int p = (sl & ~31) | ((sl & 15) << 1) | ((sl >> 4) & 1);
          Vt[(size_t)bh * 131072 + (size_t)dim * 2048 + p] = f2bf(acc[i][j][r]);
        }
      }
    }
  } else {
    unsigned short* dst = (type == 0) ? Q : Ko;
    float scale = (type == 0) ? qs : 1.0f;
#pragma unroll
    for (int i = 0; i < 4; i++) {
      int row = m0 + wm + i * 16 + kb * 4;
#pragma unroll
      for (int j = 0; j < 4; j++) {
        int dim = j * 16 + lr;
        float vals[4];
#pragma unroll
        for (int r = 0; r < 4; r++) vals[r] = acc[i][j][r];
        if (j < 2) {  // dims 0..31: rotary
          int jp = dim >> 1;
          float invf = expf(-(float)jp * 0.57564627324851142f);
#pragma unroll
          for (int r = 0; r < 4; r++) {
            int sl = (row + r) & 2047;  // sequence position
            float ang = (float)sl * invf;
            float sn, cs;
            sincosf(ang, &sn, &cs);
            float partner = __shfl_xor(vals[r], 1);
            float self = vals[r] * cs;
            vals[r] = (lr & 1) ? fmaf(partner, sn, self) : fmaf(-partner, sn, self);
          }
        }
#pragma unroll
        for (int r = 0; r < 4; r++) {
          int m = row + r;
          int b = m >> 11, sl = m & 2047;
          int bh = b * 16 + h;
          dst[(((size_t)(bh * 2048 + sl)) << 6) + dim] = f2bf(vals[r] * scale);
        }
      }
    }
  }
}

// ---------------- fused causal flash attention, v10 (unchanged) -------------------
// 4 waves x 16 q-rows, 32-key tiles, dbuf async staging, 21504 B LDS,
// conflict-free layouts, per-CU-uniform qtile quarters {z,31-z,z+8,23-z}
// (sum 132), XCD-aware bh map (4 bh per XCD -> L2-resident K/V).
__global__ __launch_bounds__(256, 6) void attn_fused(const unsigned short* __restrict__ Qg,
                                                     const unsigned short* __restrict__ Kg,
                                                     const unsigned short* __restrict__ Vtg,
                                                     unsigned short* __restrict__ AO) {
  __shared__ __attribute__((aligned(16))) unsigned short Ks[2 * 2048];  // 8 KB
  __shared__ __attribute__((aligned(16))) unsigned short Vs[2 * 2048];  // 8 KB
  __shared__ __attribute__((aligned(16))) unsigned short Ps[4 * 16 * 40];  // 5 KB
  int t = threadIdx.x;
  int w = t >> 6, lane = t & 63, kb = lane >> 4, lr = lane & 15;
  int gid = blockIdx.x;
  int g3 = gid & 7;
  int b2 = (gid >> 3) & 3;
  int z = (gid >> 5) & 7;
  int quarter = gid >> 8;
  int bh = g3 * 4 + b2;
  int qtile = (quarter == 0) ? z : (quarter == 1) ? (31 - z) : (quarter == 2) ? (z + 8) : (23 - z);
  int m0 = qtile * 64;
  const unsigned short* Qb = Qg + (size_t)bh * 2048 * 64;
  const unsigned short* Kb = Kg + (size_t)bh * 2048 * 64;
  const unsigned short* Vb = Vtg + (size_t)bh * 64 * 2048;

  short8 aq0 = *(const short8*)(Qb + (size_t)(m0 + w * 16 + lr) * 64 + kb * 8);
  short8 aq1 = *(const short8*)(Qb + (size_t)(m0 + w * 16 + lr) * 64 + 32 + kb * 8);

  v4f acc[4];
  float lp[4];
#pragma unroll
  for (int n = 0; n < 4; n++) acc[n] = (v4f){0.f, 0.f, 0.f, 0.f};
#pragma unroll
  for (int r = 0; r < 4; r++) lp[r] = 0.f;

  int nkt = 2 * qtile + 2;  // 32-key tiles
  int mrow = w * 16 + kb * 4;

  int kc = t >> 5, krow_s = t & 31;
  int vc = t >> 6, vd = t & 63;
  auto stage = [&](int kt, int buf) {
    int base = buf * 2048;
    ASYNC_COPY16(&Ks[base + t * 8], Kb + (size_t)(kt * 32 + krow_s) * 64 + kc * 8);
    ASYNC_COPY16(&Vs[base + t * 8], Vb + (size_t)vd * 2048 + kt * 32 + vc * 8);
  };

  stage(0, 0);
  __syncthreads();

  unsigned short* Pw = &Ps[w * 640];
  for (int kt = 0; kt < nkt; kt++) {
    int cur = (kt & 1) * 2048;
    if (kt + 1 < nkt) stage(kt + 1, (kt + 1) & 1);
    v4f sc[2];
#pragma unroll
    for (int n2 = 0; n2 < 2; n2++) {
      int krow = n2 * 16 + lr;
      short8 bk0 = *(const short8*)&Ks[cur + (kb * 32 + krow) * 8];
      short8 bk1 = *(const short8*)&Ks[cur + ((kb + 4) * 32 + krow) * 8];
      v4f zz = (v4f){0.f, 0.f, 0.f, 0.f};
      zz = __builtin_amdgcn_mfma_f32_16x16x32_bf16(aq0, bk0, zz, 0, 0, 0);
      zz = __builtin_amdgcn_mfma_f32_16x16x32_bf16(aq1, bk1, zz, 0, 0, 0);
      sc[n2] = zz;
    }
    if (kt >= 2 * qtile) {
#pragma unroll
      for (int n2 = 0; n2 < 2; n2++)
#pragma unroll
        for (int r = 0; r < 4; r++) {
          int key = kt * 32 + n2 * 16 + lr;
          if (key > m0 + mrow + r) sc[n2][r] = -1e30f;
        }
    }
#pragma unroll
    for (int r = 0; r < 4; r++) {
      float p0 = exp2f(sc[0][r]);
      float p1 = exp2f(sc[1][r]);
      lp[r] += p0 + p1;
      __hip_bfloat162 pb = __float22bfloat162_rn(float2{p0, p1});
      *(__hip_bfloat162*)&Pw[(mrow & 15) * 40 + r * 40 + lr * 2] = pb;
    }
    short8 ap = *(const short8*)&Pw[lr * 40 + kb * 8];
#pragma unroll
    for (int dt = 0; dt < 4; dt++) {
      int d = dt * 16 + lr;
      short8 bv = *(const short8*)&Vs[cur + (kb * 64 + d) * 8];
      acc[dt] = __builtin_amdgcn_mfma_f32_16x16x32_bf16(ap, bv, acc[dt], 0, 0, 0);
    }
    __syncthreads();
  }
  int b = bh >> 4, h = bh & 15;
#pragma unroll
  for (int r = 0; r < 4; r++) {
    float s = lp[r];
#pragma unroll
    for (int off = 1; off < 16; off <<= 1) s += __shfl_xor(s, off);
    float inv = 1.0f / s;
    int qrow = m0 + mrow + r;
#pragma unroll
    for (int dt = 0; dt < 4; dt++)
      AO[(size_t)(b * 2048 + qrow) * 1024 + h * 64 + dt * 16 + lr] = f2bf(acc[dt][r] * inv);
  }
}

extern "C" void kernel_launch(void* const* d_in, const int* in_sizes, int n_in,
                              void* d_out, int out_size, void* d_ws, size_t ws_size,
                              hipStream_t stream) {
  const float* hidden = (const float*)d_in[0];
  const float* w_qkv = (const float*)d_in[1];
  const float* w_out = (const float*)d_in[2];
  float* out = (float*)d_out;
  char* ws = (char*)d_ws;
  unsigned short* hid_bf = (unsigned short*)(ws);                  //  8 MB
  unsigned short* wqkv_bf = (unsigned short*)(ws + (8ull << 20));  //  6 MB
  unsigned short* wout_bf = (unsigned short*)(ws + (14ull << 20)); //  2 MB
  unsigned short* Qb = (unsigned short*)(ws + (16ull << 20));      //  8 MB
  unsigned short* Kb = (unsigned short*)(ws + (24ull << 20));      //  8 MB
  unsigned short* Vt = (unsigned short*)(ws + (32ull << 20));      //  8 MB
  unsigned short* AO = (unsigned short*)(ws + (40ull << 20));      //  8 MB

  convert_all<<<8192, 256, 0, stream>>>(hidden, w_qkv, w_out, hid_bf, wqkv_bf, wout_bf);
  // qkv GEMM with fused rope/head-split/V-transpose epilogue
  gemm_qkv<<<dim3(24, 32), 256, 0, stream>>>(hid_bf, wqkv_bf, Qb, Kb, Vt);
  attn_fused<<<1024, 256, 0, stream>>>(Qb, Kb, Vt, AO);
  // out = attn_out @ w_out.T  (M=4096, N=1024, K=1024), fp32 out, 128x64 tiles
  gemm_bt<64><<<dim3(16, 32), 256, 0, stream>>>(AO, wout_bf, out, 4096, 1024, 1024);
}

// Round 12
// 201.934 us; speedup vs baseline: 1.0288x; 1.0198x over previous
//
#include <hip/hip_runtime.h>
#include <hip/hip_bf16.h>

typedef __attribute__((ext_vector_type(8))) short short8;
typedef __attribute__((ext_vector_type(4))) float v4f;

// async global->LDS, 16B per lane. LDS dest must be wave-uniform base + lane*16.
#define ASYNC_COPY16(ldsptr, gptr)                                                        \
  __builtin_amdgcn_global_load_lds((const __attribute__((address_space(1))) void*)(gptr), \
                                   (__attribute__((address_space(3))) void*)(ldsptr),     \
                                   16, 0, 0)

__device__ __forceinline__ unsigned short f2bf(float f) {
  unsigned int u = __float_as_uint(f);
  u += 0x7fffu + ((u >> 16) & 1u);  // RNE
  return (unsigned short)(u >> 16);
}

// ---------------- fused fp32 -> bf16 convert for all three inputs ----------------
__global__ void convert_all(const float* __restrict__ h, const float* __restrict__ wq,
                            const float* __restrict__ wo, unsigned short* __restrict__ ho,
                            unsigned short* __restrict__ wqo, unsigned short* __restrict__ woo) {
  int i = (blockIdx.x * blockDim.x + threadIdx.x) * 4;
  const float* src;
  unsigned short* dst;
  int j;
  if (i < 4194304) { src = h; dst = ho; j = i; }
  else if (i < 7340032) { src = wq; dst = wqo; j = i - 4194304; }
  else { src = wo; dst = woo; j = i - 7340032; }
  float4 v = *(const float4*)(src + j);
  ushort4 o;
  o.x = f2bf(v.x); o.y = f2bf(v.y); o.z = f2bf(v.z); o.w = f2bf(v.w);
  *(ushort4*)(dst + j) = o;
}

// GEMM LDS bank swizzle (round 11, verified conflicts -> 0): global chunk c of
// local row r lives at LDS chunk c ^ ((r>>1)&3).
#define STAGE_SWZ(tt) ((((tt) & 3) ^ (((tt) >> 3) & 3)) * 8)
#define READ_SWZ(kb, lr) (((kb) ^ (((lr) >> 1) & 3)) * 8)

// ---------------- out-proj GEMM: 64x64 tiles for TLP (1024 blocks = 4/CU) ---------
// C[m][n] = sum_k A[m][k]*B[n][k], A bf16, fp32 out. Wave = 32x32 (acc 2x2).
__global__ __launch_bounds__(256, 6) void gemm_out(const unsigned short* __restrict__ A,
                                                   const unsigned short* __restrict__ Bm,
                                                   float* __restrict__ C, int M, int N, int K) {
  __shared__ __attribute__((aligned(16))) unsigned short As[64 * 32];
  __shared__ __attribute__((aligned(16))) unsigned short Bs[64 * 32];
  int t = threadIdx.x;
  int w = t >> 6, lane = t & 63, kb = lane >> 4, lr = lane & 15;
  int m0 = blockIdx.y * 64, n0 = blockIdx.x * 64;
  int wm = (w >> 1) * 32, wn = (w & 1) * 32;
  v4f acc[2][2];
#pragma unroll
  for (int i = 0; i < 2; i++)
#pragma unroll
    for (int j = 0; j < 2; j++) acc[i][j] = (v4f){0.f, 0.f, 0.f, 0.f};
  int ra = m0 + (t >> 2);
  int rb = n0 + (t >> 2);
  int ca = STAGE_SWZ(t);
  int rs = READ_SWZ(kb, lr);
  for (int k0 = 0; k0 < K; k0 += 32) {
    ASYNC_COPY16(&As[t * 8], A + (size_t)ra * K + k0 + ca);
    ASYNC_COPY16(&Bs[t * 8], Bm + (size_t)rb * K + k0 + ca);
    __syncthreads();
    short8 av[2], bv[2];
#pragma unroll
    for (int i = 0; i < 2; i++) av[i] = *(const short8*)&As[(wm + i * 16 + lr) * 32 + rs];
#pragma unroll
    for (int j = 0; j < 2; j++) bv[j] = *(const short8*)&Bs[(wn + j * 16 + lr) * 32 + rs];
#pragma unroll
    for (int i = 0; i < 2; i++)
#pragma unroll
      for (int j = 0; j < 2; j++)
        acc[i][j] = __builtin_amdgcn_mfma_f32_16x16x32_bf16(av[i], bv[j], acc[i][j], 0, 0, 0);
    __syncthreads();
  }
#pragma unroll
  for (int i = 0; i < 2; i++) {
    int row = m0 + wm + i * 16 + kb * 4;
#pragma unroll
    for (int j = 0; j < 2; j++) {
      int col = n0 + wn + j * 16 + lr;
#pragma unroll
      for (int r = 0; r < 4; r++) C[(size_t)(row + r) * N + col] = acc[i][j][r];
    }
  }
}

// ---------- QKV GEMM (128x64 tiles, 1536 blocks = 6/CU) + FUSED rope/split/Vt ------
// C = hidden @ w_qkv.T (M=4096, N=3072, K=1024). Each 64-wide n-tile is one
// head of one type: X = n0/64, mp = X/6, sub = X%6, type = sub>>1 (0=q,1=v,2=k),
// ii = sub&1, h = mp*2+ii. Epilogue applies RoPE to q/k (pair exchange via
// shfl_xor(1)) and writes Q (pre-scaled log2e/8), K, key-permuted transposed Vt.
__global__ __launch_bounds__(256, 6) void gemm_qkv(const unsigned short* __restrict__ A,
                                                   const unsigned short* __restrict__ Bm,
                                                   unsigned short* __restrict__ Q,
                                                   unsigned short* __restrict__ Ko,
                                                   unsigned short* __restrict__ Vt) {
  constexpr int Kd = 1024;
  __shared__ __attribute__((aligned(16))) unsigned short As[128 * 32];
  __shared__ __attribute__((aligned(16))) unsigned short Bs[64 * 32];
  int t = threadIdx.x;
  int w = t >> 6, lane = t & 63, kb = lane >> 4, lr = lane & 15;
  int m0 = blockIdx.y * 128, n0 = blockIdx.x * 64;
  int wm = (w >> 1) * 64, wn = (w & 1) * 32;
  v4f acc[4][2];
#pragma unroll
  for (int i = 0; i < 4; i++)
#pragma unroll
    for (int j = 0; j < 2; j++) acc[i][j] = (v4f){0.f, 0.f, 0.f, 0.f};
  int ra = m0 + (t >> 2);
  int rb = n0 + (t >> 2);
  int ca = STAGE_SWZ(t);
  int rs = READ_SWZ(kb, lr);
  for (int k0 = 0; k0 < Kd; k0 += 32) {
    ASYNC_COPY16(&As[t * 8],        A + (size_t)ra * Kd + k0 + ca);
    ASYNC_COPY16(&As[2048 + t * 8], A + (size_t)(ra + 64) * Kd + k0 + ca);
    ASYNC_COPY16(&Bs[t * 8],        Bm + (size_t)rb * Kd + k0 + ca);
    __syncthreads();
    short8 av[4], bv[2];
#pragma unroll
    for (int i = 0; i < 4; i++) av[i] = *(const short8*)&As[(wm + i * 16 + lr) * 32 + rs];
#pragma unroll
    for (int j = 0; j < 2; j++) bv[j] = *(const short8*)&Bs[(wn + j * 16 + lr) * 32 + rs];
#pragma unroll
    for (int i = 0; i < 4; i++)
#pragma unroll
      for (int j = 0; j < 2; j++)
        acc[i][j] = __builtin_amdgcn_mfma_f32_16x16x32_bf16(av[i], bv[j], acc[i][j], 0, 0, 0);
    __syncthreads();
  }
  // ---- fused epilogue (block-uniform type/head) ----
  int X = n0 >> 6;
  int mp = X / 6;
  int sub = X - mp * 6;
  int type = sub >> 1;  // 0=q, 1=v, 2=k
  int ii = sub & 1;
  int h = mp * 2 + ii;
  const float qs = 0.125f * 1.4426950408889634f;  // 1/sqrt(64) * log2(e)
  if (type == 1) {
    // V: Vt[bh][dim][perm(s)], perm = (s&~31) | ((s&15)<<1) | ((s>>4)&1)
#pragma unroll
    for (int i = 0; i < 4; i++) {
      int row = m0 + wm + i * 16 + kb * 4;
#pragma unroll
      for (int j = 0; j < 2; j++) {
        int dim = wn + j * 16 + lr;
#pragma unroll
        for (int r = 0; r < 4; r++) {
          int m = row + r;
          int b = m >> 11, sl = m & 2047;
          int bh = b * 16 + h;
          int p = (sl & ~31) | ((sl & 15) << 1) | ((sl >> 4) & 1);
          Vt[(size_t)bh * 131072 + (size_t)dim * 2048 + p] = f2bf(acc[i][j][r]);
        }
      }
    }
  } else {
    unsigned short* dst = (type == 0) ? Q : Ko;
    float scale = (type == 0) ? qs : 1.0f;
#pragma unroll
    for (int i = 0; i < 4; i++) {
      int row = m0 + wm + i * 16 + kb * 4;
#pragma unroll
      for (int j = 0; j < 2; j++) {
        int dim = wn + j * 16 + lr;
        float vals[4];
#pragma unroll
        for (int r = 0; r < 4; r++) vals[r] = acc[i][j][r];
        if (dim < 32) {  // rotary dims
          int jp = dim >> 1;
          float invf = expf(-(float)jp * 0.57564627324851142f);
#pragma unroll
          for (int r = 0; r < 4; r++) {
            int sl = (row + r) & 2047;
            float ang = (float)sl * invf;
            float sn, cs;
            sincosf(ang, &sn, &cs);
            float partner = __shfl_xor(vals[r], 1);
            float self = vals[r] * cs;
            vals[r] = (lr & 1) ? fmaf(partner, sn, self) : fmaf(-partner, sn, self);
          }
        }
#pragma unroll
        for (int r = 0; r < 4; r++) {
          int m = row + r;
          int b = m >> 11, sl = m & 2047;
          int bh = b * 16 + h;
          dst[(((size_t)(bh * 2048 + sl)) << 6) + dim] = f2bf(vals[r] * scale);
        }
      }
    }
  }
}

// ---------------- fused causal flash attention, v10 (unchanged) -------------------
// 4 waves x 16 q-rows, 32-key tiles, dbuf async staging, 21504 B LDS,
// conflict-free layouts, per-CU-uniform qtile quarters {z,31-z,z+8,23-z}
// (sum 132), XCD-aware bh map (4 bh per XCD -> L2-resident K/V).
__global__ __launch_bounds__(256, 6) void attn_fused(const unsigned short* __restrict__ Qg,
                                                     const unsigned short* __restrict__ Kg,
                                                     const unsigned short* __restrict__ Vtg,
                                                     unsigned short* __restrict__ AO) {
  __shared__ __attribute__((aligned(16))) unsigned short Ks[2 * 2048];  // 8 KB
  __shared__ __attribute__((aligned(16))) unsigned short Vs[2 * 2048];  // 8 KB
  __shared__ __attribute__((aligned(16))) unsigned short Ps[4 * 16 * 40];  // 5 KB
  int t = threadIdx.x;
  int w = t >> 6, lane = t & 63, kb = lane >> 4, lr = lane & 15;
  int gid = blockIdx.x;
  int g3 = gid & 7;
  int b2 = (gid >> 3) & 3;
  int z = (gid >> 5) & 7;
  int quarter = gid >> 8;
  int bh = g3 * 4 + b2;
  int qtile = (quarter == 0) ? z : (quarter == 1) ? (31 - z) : (quarter == 2) ? (z + 8) : (23 - z);
  int m0 = qtile * 64;
  const unsigned short* Qb = Qg + (size_t)bh * 2048 * 64;
  const unsigned short* Kb = Kg + (size_t)bh * 2048 * 64;
  const unsigned short* Vb = Vtg + (size_t)bh * 64 * 2048;

  short8 aq0 = *(const short8*)(Qb + (size_t)(m0 + w * 16 + lr) * 64 + kb * 8);
  short8 aq1 = *(const short8*)(Qb + (size_t)(m0 + w * 16 + lr) * 64 + 32 + kb * 8);

  v4f acc[4];
  float lp[4];
#pragma unroll
  for (int n = 0; n < 4; n++) acc[n] = (v4f){0.f, 0.f, 0.f, 0.f};
#pragma unroll
  for (int r = 0; r < 4; r++) lp[r] = 0.f;

  int nkt = 2 * qtile + 2;  // 32-key tiles
  int mrow = w * 16 + kb * 4;

  int kc = t >> 5, krow_s = t & 31;
  int vc = t >> 6, vd = t & 63;
  auto stage = [&](int kt, int buf) {
    int base = buf * 2048;
    ASYNC_COPY16(&Ks[base + t * 8], Kb + (size_t)(kt * 32 + krow_s) * 64 + kc * 8);
    ASYNC_COPY16(&Vs[base + t * 8], Vb + (size_t)vd * 2048 + kt * 32 + vc * 8);
  };

  stage(0, 0);
  __syncthreads();

  unsigned short* Pw = &Ps[w * 640];
  for (int kt = 0; kt < nkt; kt++) {
    int cur = (kt & 1) * 2048;
    if (kt + 1 < nkt) stage(kt + 1, (kt + 1) & 1);
    v4f sc[2];
#pragma unroll
    for (int n2 = 0; n2 < 2; n2++) {
      int krow = n2 * 16 + lr;
      short8 bk0 = *(const short8*)&Ks[cur + (kb * 32 + krow) * 8];
      short8 bk1 = *(const short8*)&Ks[cur + ((kb + 4) * 32 + krow) * 8];
      v4f zz = (v4f){0.f, 0.f, 0.f, 0.f};
      zz = __builtin_amdgcn_mfma_f32_16x16x32_bf16(aq0, bk0, zz, 0, 0, 0);
      zz = __builtin_amdgcn_mfma_f32_16x16x32_bf16(aq1, bk1, zz, 0, 0, 0);
      sc[n2] = zz;
    }
    if (kt >= 2 * qtile) {
#pragma unroll
      for (int n2 = 0; n2 < 2; n2++)
#pragma unroll
        for (int r = 0; r < 4; r++) {
          int key = kt * 32 + n2 * 16 + lr;
          if (key > m0 + mrow + r) sc[n2][r] = -1e30f;
        }
    }
#pragma unroll
    for (int r = 0; r < 4; r++) {
      float p0 = exp2f(sc[0][r]);
      float p1 = exp2f(sc[1][r]);
      lp[r] += p0 + p1;
      __hip_bfloat162 pb = __float22bfloat162_rn(float2{p0, p1});
      *(__hip_bfloat162*)&Pw[(mrow & 15) * 40 + r * 40 + lr * 2] = pb;
    }
    short8 ap = *(const short8*)&Pw[lr * 40 + kb * 8];
#pragma unroll
    for (int dt = 0; dt < 4; dt++) {
      int d = dt * 16 + lr;
      short8 bv = *(const short8*)&Vs[cur + (kb * 64 + d) * 8];
      acc[dt] = __builtin_amdgcn_mfma_f32_16x16x32_bf16(ap, bv, acc[dt], 0, 0, 0);
    }
    __syncthreads();
  }
  int b = bh >> 4, h = bh & 15;
#pragma unroll
  for (int r = 0; r < 4; r++) {
    float s = lp[r];
#pragma unroll
    for (int off = 1; off < 16; off <<= 1) s += __shfl_xor(s, off);
    float inv = 1.0f / s;
    int qrow = m0 + mrow + r;
#pragma unroll
    for (int dt = 0; dt < 4; dt++)
      AO[(size_t)(b * 2048 + qrow) * 1024 + h * 64 + dt * 16 + lr] = f2bf(acc[dt][r] * inv);
  }
}

extern "C" void kernel_launch(void* const* d_in, const int* in_sizes, int n_in,
                              void* d_out, int out_size, void* d_ws, size_t ws_size,
                              hipStream_t stream) {
  const float* hidden = (const float*)d_in[0];
  const float* w_qkv = (const float*)d_in[1];
  const float* w_out = (const float*)d_in[2];
  float* out = (float*)d_out;
  char* ws = (char*)d_ws;
  unsigned short* hid_bf = (unsigned short*)(ws);                  //  8 MB
  unsigned short* wqkv_bf = (unsigned short*)(ws + (8ull << 20));  //  6 MB
  unsigned short* wout_bf = (unsigned short*)(ws + (14ull << 20)); //  2 MB
  unsigned short* Qb = (unsigned short*)(ws + (16ull << 20));      //  8 MB
  unsigned short* Kb = (unsigned short*)(ws + (24ull << 20));      //  8 MB
  unsigned short* Vt = (unsigned short*)(ws + (32ull << 20));      //  8 MB
  unsigned short* AO = (unsigned short*)(ws + (40ull << 20));      //  8 MB

  convert_all<<<8192, 256, 0, stream>>>(hidden, w_qkv, w_out, hid_bf, wqkv_bf, wout_bf);
  // qkv GEMM with fused rope/head-split/V-transpose epilogue (128x64 tiles, 6/CU)
  gemm_qkv<<<dim3(48, 32), 256, 0, stream>>>(hid_bf, wqkv_bf, Qb, Kb, Vt);
  attn_fused<<<1024, 256, 0, stream>>>(Qb, Kb, Vt, AO);
  // out = attn_out @ w_out.T  (M=4096, N=1024, K=1024), 64x64 tiles, 4/CU
  gemm_out<<<dim3(16, 64), 256, 0, stream>>>(AO, wout_bf, out, 4096, 1024, 1024);
}

// Round 13
// 192.903 us; speedup vs baseline: 1.0770x; 1.0468x over previous
//
#include <hip/hip_runtime.h>
#include <hip/hip_bf16.h>

typedef __attribute__((ext_vector_type(8))) short short8;
typedef __attribute__((ext_vector_type(4))) float v4f;

// async global->LDS, 16B per lane. LDS dest must be wave-uniform base + lane*16.
#define ASYNC_COPY16(ldsptr, gptr)                                                        \
  __builtin_amdgcn_global_load_lds((const __attribute__((address_space(1))) void*)(gptr), \
                                   (__attribute__((address_space(3))) void*)(ldsptr),     \
                                   16, 0, 0)

__device__ __forceinline__ unsigned short f2bf(float f) {
  unsigned int u = __float_as_uint(f);
  u += 0x7fffu + ((u >> 16) & 1u);  // RNE
  return (unsigned short)(u >> 16);
}

// ---------------- fused fp32 -> bf16 convert for all three inputs ----------------
__global__ void convert_all(const float* __restrict__ h, const float* __restrict__ wq,
                            const float* __restrict__ wo, unsigned short* __restrict__ ho,
                            unsigned short* __restrict__ wqo, unsigned short* __restrict__ woo) {
  int i = (blockIdx.x * blockDim.x + threadIdx.x) * 4;
  const float* src;
  unsigned short* dst;
  int j;
  if (i < 4194304) { src = h; dst = ho; j = i; }
  else if (i < 7340032) { src = wq; dst = wqo; j = i - 4194304; }
  else { src = wo; dst = woo; j = i - 7340032; }
  float4 v = *(const float4*)(src + j);
  ushort4 o;
  o.x = f2bf(v.x); o.y = f2bf(v.y); o.z = f2bf(v.z); o.w = f2bf(v.w);
  *(ushort4*)(dst + j) = o;
}

// GEMM LDS bank swizzle (round 11, verified conflicts -> 0)
#define STAGE_SWZ(tt) ((((tt) & 3) ^ (((tt) >> 3) & 3)) * 8)
#define READ_SWZ(kb, lr) (((kb) ^ (((lr) >> 1) & 3)) * 8)

// ---------------- out-proj GEMM: 64x64 tiles (1024 blocks = 4/CU) ----------------
__global__ __launch_bounds__(256, 6) void gemm_out(const unsigned short* __restrict__ A,
                                                   const unsigned short* __restrict__ Bm,
                                                   float* __restrict__ C, int M, int N, int K) {
  __shared__ __attribute__((aligned(16))) unsigned short As[64 * 32];
  __shared__ __attribute__((aligned(16))) unsigned short Bs[64 * 32];
  int t = threadIdx.x;
  int w = t >> 6, lane = t & 63, kb = lane >> 4, lr = lane & 15;
  int m0 = blockIdx.y * 64, n0 = blockIdx.x * 64;
  int wm = (w >> 1) * 32, wn = (w & 1) * 32;
  v4f acc[2][2];
#pragma unroll
  for (int i = 0; i < 2; i++)
#pragma unroll
    for (int j = 0; j < 2; j++) acc[i][j] = (v4f){0.f, 0.f, 0.f, 0.f};
  int ra = m0 + (t >> 2);
  int rb = n0 + (t >> 2);
  int ca = STAGE_SWZ(t);
  int rs = READ_SWZ(kb, lr);
  for (int k0 = 0; k0 < K; k0 += 32) {
    ASYNC_COPY16(&As[t * 8], A + (size_t)ra * K + k0 + ca);
    ASYNC_COPY16(&Bs[t * 8], Bm + (size_t)rb * K + k0 + ca);
    __syncthreads();
    short8 av[2], bv[2];
#pragma unroll
    for (int i = 0; i < 2; i++) av[i] = *(const short8*)&As[(wm + i * 16 + lr) * 32 + rs];
#pragma unroll
    for (int j = 0; j < 2; j++) bv[j] = *(const short8*)&Bs[(wn + j * 16 + lr) * 32 + rs];
#pragma unroll
    for (int i = 0; i < 2; i++)
#pragma unroll
      for (int j = 0; j < 2; j++)
        acc[i][j] = __builtin_amdgcn_mfma_f32_16x16x32_bf16(av[i], bv[j], acc[i][j], 0, 0, 0);
    __syncthreads();
  }
#pragma unroll
  for (int i = 0; i < 2; i++) {
    int row = m0 + wm + i * 16 + kb * 4;
#pragma unroll
    for (int j = 0; j < 2; j++) {
      int col = n0 + wn + j * 16 + lr;
#pragma unroll
      for (int r = 0; r < 4; r++) C[(size_t)(row + r) * N + col] = acc[i][j][r];
    }
  }
}

// ---------- QKV GEMM (128x64 tiles, 1536 blocks = 6/CU) + FUSED rope/split/Vt ------
__global__ __launch_bounds__(256, 6) void gemm_qkv(const unsigned short* __restrict__ A,
                                                   const unsigned short* __restrict__ Bm,
                                                   unsigned short* __restrict__ Q,
                                                   unsigned short* __restrict__ Ko,
                                                   unsigned short* __restrict__ Vt) {
  constexpr int Kd = 1024;
  __shared__ __attribute__((aligned(16))) unsigned short As[128 * 32];
  __shared__ __attribute__((aligned(16))) unsigned short Bs[64 * 32];
  int t = threadIdx.x;
  int w = t >> 6, lane = t & 63, kb = lane >> 4, lr = lane & 15;
  int m0 = blockIdx.y * 128, n0 = blockIdx.x * 64;
  int wm = (w >> 1) * 64, wn = (w & 1) * 32;
  v4f acc[4][2];
#pragma unroll
  for (int i = 0; i < 4; i++)
#pragma unroll
    for (int j = 0; j < 2; j++) acc[i][j] = (v4f){0.f, 0.f, 0.f, 0.f};
  int ra = m0 + (t >> 2);
  int rb = n0 + (t >> 2);
  int ca = STAGE_SWZ(t);
  int rs = READ_SWZ(kb, lr);
  for (int k0 = 0; k0 < Kd; k0 += 32) {
    ASYNC_COPY16(&As[t * 8],        A + (size_t)ra * Kd + k0 + ca);
    ASYNC_COPY16(&As[2048 + t * 8], A + (size_t)(ra + 64) * Kd + k0 + ca);
    ASYNC_COPY16(&Bs[t * 8],        Bm + (size_t)rb * Kd + k0 + ca);
    __syncthreads();
    short8 av[4], bv[2];
#pragma unroll
    for (int i = 0; i < 4; i++) av[i] = *(const short8*)&As[(wm + i * 16 + lr) * 32 + rs];
#pragma unroll
    for (int j = 0; j < 2; j++) bv[j] = *(const short8*)&Bs[(wn + j * 16 + lr) * 32 + rs];
#pragma unroll
    for (int i = 0; i < 4; i++)
#pragma unroll
      for (int j = 0; j < 2; j++)
        acc[i][j] = __builtin_amdgcn_mfma_f32_16x16x32_bf16(av[i], bv[j], acc[i][j], 0, 0, 0);
    __syncthreads();
  }
  // ---- fused epilogue (block-uniform type/head) ----
  int X = n0 >> 6;
  int mp = X / 6;
  int sub = X - mp * 6;
  int type = sub >> 1;  // 0=q, 1=v, 2=k
  int ii = sub & 1;
  int h = mp * 2 + ii;
  const float qs = 0.125f * 1.4426950408889634f;  // 1/sqrt(64) * log2(e)
  if (type == 1) {
#pragma unroll
    for (int i = 0; i < 4; i++) {
      int row = m0 + wm + i * 16 + kb * 4;
#pragma unroll
      for (int j = 0; j < 2; j++) {
        int dim = wn + j * 16 + lr;
#pragma unroll
        for (int r = 0; r < 4; r++) {
          int m = row + r;
          int b = m >> 11, sl = m & 2047;
          int bh = b * 16 + h;
          int p = (sl & ~31) | ((sl & 15) << 1) | ((sl >> 4) & 1);
          Vt[(size_t)bh * 131072 + (size_t)dim * 2048 + p] = f2bf(acc[i][j][r]);
        }
      }
    }
  } else {
    unsigned short* dst = (type == 0) ? Q : Ko;
    float scale = (type == 0) ? qs : 1.0f;
#pragma unroll
    for (int i = 0; i < 4; i++) {
      int row = m0 + wm + i * 16 + kb * 4;
#pragma unroll
      for (int j = 0; j < 2; j++) {
        int dim = wn + j * 16 + lr;
        float vals[4];
#pragma unroll
        for (int r = 0; r < 4; r++) vals[r] = acc[i][j][r];
        if (dim < 32) {  // rotary dims
          int jp = dim >> 1;
          float invf = expf(-(float)jp * 0.57564627324851142f);
#pragma unroll
          for (int r = 0; r < 4; r++) {
            int sl = (row + r) & 2047;
            float ang = (float)sl * invf;
            float sn, cs;
            sincosf(ang, &sn, &cs);
            float partner = __shfl_xor(vals[r], 1);
            float self = vals[r] * cs;
            vals[r] = (lr & 1) ? fmaf(partner, sn, self) : fmaf(-partner, sn, self);
          }
        }
#pragma unroll
        for (int r = 0; r < 4; r++) {
          int m = row + r;
          int b = m >> 11, sl = m & 2047;
          int bh = b * 16 + h;
          dst[(((size_t)(bh * 2048 + sl)) << 6) + dim] = f2bf(vals[r] * scale);
        }
      }
    }
  }
}

// ---------------- fused causal flash attention, v11: split-key long tiles ---------
// Per bh, 48 blocks (1536 total = 6/CU, 24 waves/CU):
//   j<16:       full qtile q=j, tiles [0, 2q+2), normalized bf16 AO write.
//   j in 16..31: LOWER half of qtile q=j, tiles [0, q+1)      -> fp32 partials.
//   j in 32..47: UPPER half of qtile q=j-16, tiles [q+1, 2q+2) -> fp32 partials
//                (carries the diagonal mask).
// No-running-max softmax => partials are exactly additive; combine kernel does
// (PO0+PO1)/(PL0+PL1). Max serial block length 64 -> 34 iters. Per-CU-uniform
// coset map {2z, 15-2z, 16+z, 31-z, 32+z, 47-z}: every z sums to 132 iters;
// all 6 co-resident blocks share bh (XCD/L2 map from v10 kept: FETCH 62->12MB).
__global__ __launch_bounds__(256, 6) void attn_fused(const unsigned short* __restrict__ Qg,
                                                     const unsigned short* __restrict__ Kg,
                                                     const unsigned short* __restrict__ Vtg,
                                                     unsigned short* __restrict__ AO,
                                                     float* __restrict__ PO,
                                                     float* __restrict__ PL) {
  __shared__ __attribute__((aligned(16))) unsigned short Ks[2 * 2048];  // 8 KB
  __shared__ __attribute__((aligned(16))) unsigned short Vs[2 * 2048];  // 8 KB
  __shared__ __attribute__((aligned(16))) unsigned short Ps[4 * 16 * 40];  // 5 KB
  int t = threadIdx.x;
  int w = t >> 6, lane = t & 63, kb = lane >> 4, lr = lane & 15;
  int gid = blockIdx.x;
  int g3 = gid & 7;
  int b2 = (gid >> 3) & 3;
  int z = (gid >> 5) & 7;
  int coset = gid >> 8;  // 0..5
  int bh = g3 * 4 + b2;
  int j = (coset == 0) ? (2 * z)
        : (coset == 1) ? (15 - 2 * z)
        : (coset == 2) ? (16 + z)
        : (coset == 3) ? (31 - z)
        : (coset == 4) ? (32 + z)
                       : (47 - z);
  int qtile, kt0, kt1, mode;  // mode 0=full, 1=lower-half, 2=upper-half
  if (j < 16)      { qtile = j;      mode = 0; kt0 = 0;          kt1 = 2 * qtile + 2; }
  else if (j < 32) { qtile = j;      mode = 1; kt0 = 0;          kt1 = qtile + 1; }
  else             { qtile = j - 16; mode = 2; kt0 = qtile + 1;  kt1 = 2 * qtile + 2; }
  int m0 = qtile * 64;
  const unsigned short* Qb = Qg + (size_t)bh * 2048 * 64;
  const unsigned short* Kb = Kg + (size_t)bh * 2048 * 64;
  const unsigned short* Vb = Vtg + (size_t)bh * 64 * 2048;

  short8 aq0 = *(const short8*)(Qb + (size_t)(m0 + w * 16 + lr) * 64 + kb * 8);
  short8 aq1 = *(const short8*)(Qb + (size_t)(m0 + w * 16 + lr) * 64 + 32 + kb * 8);

  v4f acc[4];
  float lp[4];
#pragma unroll
  for (int n = 0; n < 4; n++) acc[n] = (v4f){0.f, 0.f, 0.f, 0.f};
#pragma unroll
  for (int r = 0; r < 4; r++) lp[r] = 0.f;

  int mrow = w * 16 + kb * 4;

  int kc = t >> 5, krow_s = t & 31;
  int vc = t >> 6, vd = t & 63;
  auto stage = [&](int kt, int buf) {
    int base = buf * 2048;
    ASYNC_COPY16(&Ks[base + t * 8], Kb + (size_t)(kt * 32 + krow_s) * 64 + kc * 8);
    ASYNC_COPY16(&Vs[base + t * 8], Vb + (size_t)vd * 2048 + kt * 32 + vc * 8);
  };

  stage(kt0, 0);
  __syncthreads();

  unsigned short* Pw = &Ps[w * 640];
  int niter = kt1 - kt0;
  for (int it = 0; it < niter; it++) {
    int kt = kt0 + it;
    int cur = (it & 1) * 2048;
    if (it + 1 < niter) stage(kt + 1, (it + 1) & 1);
    v4f sc[2];
#pragma unroll
    for (int n2 = 0; n2 < 2; n2++) {
      int krow = n2 * 16 + lr;
      short8 bk0 = *(const short8*)&Ks[cur + (kb * 32 + krow) * 8];
      short8 bk1 = *(const short8*)&Ks[cur + ((kb + 4) * 32 + krow) * 8];
      v4f zz = (v4f){0.f, 0.f, 0.f, 0.f};
      zz = __builtin_amdgcn_mfma_f32_16x16x32_bf16(aq0, bk0, zz, 0, 0, 0);
      zz = __builtin_amdgcn_mfma_f32_16x16x32_bf16(aq1, bk1, zz, 0, 0, 0);
      sc[n2] = zz;
    }
    if (kt >= 2 * qtile) {  // diagonal-overlap tiles (only mode 0/2 reach here)
#pragma unroll
      for (int n2 = 0; n2 < 2; n2++)
#pragma unroll
        for (int r = 0; r < 4; r++) {
          int key = kt * 32 + n2 * 16 + lr;
          if (key > m0 + mrow + r) sc[n2][r] = -1e30f;
        }
    }
#pragma unroll
    for (int r = 0; r < 4; r++) {
      float p0 = exp2f(sc[0][r]);
      float p1 = exp2f(sc[1][r]);
      lp[r] += p0 + p1;
      __hip_bfloat162 pb = __float22bfloat162_rn(float2{p0, p1});
      *(__hip_bfloat162*)&Pw[(mrow & 15) * 40 + r * 40 + lr * 2] = pb;
    }
    short8 ap = *(const short8*)&Pw[lr * 40 + kb * 8];
#pragma unroll
    for (int dt = 0; dt < 4; dt++) {
      int d = dt * 16 + lr;
      short8 bv = *(const short8*)&Vs[cur + (kb * 64 + d) * 8];
      acc[dt] = __builtin_amdgcn_mfma_f32_16x16x32_bf16(ap, bv, acc[dt], 0, 0, 0);
    }
    __syncthreads();
  }
  // row-sum reduction (16 lanes share a row)
  float s[4];
#pragma unroll
  for (int r = 0; r < 4; r++) {
    s[r] = lp[r];
#pragma unroll
    for (int off = 1; off < 16; off <<= 1) s[r] += __shfl_xor(s[r], off);
  }
  if (mode == 0) {
    int b = bh >> 4, h = bh & 15;
#pragma unroll
    for (int r = 0; r < 4; r++) {
      float inv = 1.0f / s[r];
      int qrow = m0 + mrow + r;
#pragma unroll
      for (int dt = 0; dt < 4; dt++)
        AO[(size_t)(b * 2048 + qrow) * 1024 + h * 64 + dt * 16 + lr] = f2bf(acc[dt][r] * inv);
    }
  } else {
    int hf = mode - 1;
    size_t pbase = ((size_t)hf * 512 + bh * 16 + (qtile - 16)) * 4096;  // *64rows*64d
    size_t plbase = (size_t)hf * 32768 + (bh * 16 + (qtile - 16)) * 64;
#pragma unroll
    for (int r = 0; r < 4; r++) {
      if (lr == 0) PL[plbase + mrow + r] = s[r];
#pragma unroll
      for (int dt = 0; dt < 4; dt++)
        PO[pbase + (size_t)(mrow + r) * 64 + dt * 16 + lr] = acc[dt][r];
    }
  }
}

// ---------------- split-key combine: AO rows 1024..2047 per bh -------------------
__global__ __launch_bounds__(256) void combine(const float* __restrict__ PO,
                                               const float* __restrict__ PL,
                                               unsigned short* __restrict__ AO) {
  int idx = blockIdx.x * 256 + threadIdx.x;  // 524288 threads, 4 d each
  int d4 = (idx & 15) * 4;
  int row10 = (idx >> 4) & 1023;
  int bh = idx >> 14;
  int q16 = row10 >> 6, lrow = row10 & 63;
  size_t pbase = (((size_t)(bh * 16 + q16)) * 64 + lrow) * 64 + d4;
  float4 a = *(const float4*)&PO[pbase];
  float4 c = *(const float4*)&PO[2097152 + pbase];
  float l = PL[(bh * 16 + q16) * 64 + lrow] + PL[32768 + (bh * 16 + q16) * 64 + lrow];
  float inv = 1.0f / l;
  ushort4 o;
  o.x = f2bf((a.x + c.x) * inv);
  o.y = f2bf((a.y + c.y) * inv);
  o.z = f2bf((a.z + c.z) * inv);
  o.w = f2bf((a.w + c.w) * inv);
  int b = bh >> 4, h = bh & 15;
  int qrow = 1024 + row10;
  *(ushort4*)&AO[(size_t)(b * 2048 + qrow) * 1024 + h * 64 + d4] = o;
}

extern "C" void kernel_launch(void* const* d_in, const int* in_sizes, int n_in,
                              void* d_out, int out_size, void* d_ws, size_t ws_size,
                              hipStream_t stream) {
  const float* hidden = (const float*)d_in[0];
  const float* w_qkv = (const float*)d_in[1];
  const float* w_out = (const float*)d_in[2];
  float* out = (float*)d_out;
  char* ws = (char*)d_ws;
  unsigned short* hid_bf = (unsigned short*)(ws);                  //  8 MB
  unsigned short* wqkv_bf = (unsigned short*)(ws + (8ull << 20));  //  6 MB
  unsigned short* wout_bf = (unsigned short*)(ws + (14ull << 20)); //  2 MB
  unsigned short* Qb = (unsigned short*)(ws + (16ull << 20));      //  8 MB
  unsigned short* Kb = (unsigned short*)(ws + (24ull << 20));      //  8 MB
  unsigned short* Vt = (unsigned short*)(ws + (32ull << 20));      //  8 MB
  unsigned short* AO = (unsigned short*)(ws + (40ull << 20));      //  8 MB
  float* PO = (float*)(ws + (48ull << 20));                        // 16 MB
  float* PL = (float*)(ws + (64ull << 20));                        // 256 KB

  convert_all<<<8192, 256, 0, stream>>>(hidden, w_qkv, w_out, hid_bf, wqkv_bf, wout_bf);
  gemm_qkv<<<dim3(48, 32), 256, 0, stream>>>(hid_bf, wqkv_bf, Qb, Kb, Vt);
  attn_fused<<<1536, 256, 0, stream>>>(Qb, Kb, Vt, AO, PO, PL);
  combine<<<2048, 256, 0, stream>>>(PO, PL, AO);
  gemm_out<<<dim3(16, 64), 256, 0, stream>>>(AO, wout_bf, out, 4096, 1024, 1024);
}